// Round 20
// baseline (42.670 us; speedup 1.0000x reference)
//
#include <hip/hip_runtime.h>
#include <math.h>

typedef float f32x2 __attribute__((ext_vector_type(2)));

#define A_HEADS 8
#define BB 32
#define HH 160
#define WW 160

// DIAGNOSTIC ROUND: champion kernel with idempotently-duplicated grid
// (grid.y doubled; second copy recomputes and rewrites identical values).
// Purpose: make vi_kernel the longest dispatch (~51us > 39us poison fills)
// so rocprof's top-5 finally shows ITS VALUBusy/Occupancy/VGPR at the
// champion's exact inner-loop code. Output remains byte-identical.
__global__ __launch_bounds__(256) void vi_kernel(
    const float* __restrict__ values,
    const float* __restrict__ rewards,
    const float* __restrict__ weight,
    float* __restrict__ out)
{
    int by = blockIdx.y;
    if (by >= (BB * HH) / 8) by -= (BB * HH) / 8;   // duplicate half maps to same rows

    int w  = blockIdx.x * 32 + threadIdx.x;   // 0..159 (grid.x = 5)
    int hb = by * 8 + threadIdx.y;            // 0..B*H-1
    int h  = hb % HH;
    int b  = hb / HH;

    const float* vbase = values  + b * (HH * WW);
    const float* rbase = rewards + b * (HH * WW);

    // 3x3 zero-padded patch of rv = values + rewards around (h, w)
    float patch[9];
    #pragma unroll
    for (int di = 0; di < 3; ++di) {
        int hh = h + di - 1;
        bool hok = (hh >= 0) && (hh < HH);
        #pragma unroll
        for (int dj = 0; dj < 3; ++dj) {
            int ww = w + dj - 1;
            bool ok = hok && (ww >= 0) && (ww < WW);
            float val = 0.0f;
            if (ok) {
                int off = hh * WW + ww;
                val = vbase[off] + rbase[off];
            }
            patch[di * 3 + dj] = val;
        }
    }

    // patch pairs (j, j+1), built once, reused by all 72 logits
    f32x2 patchp[4];
    #pragma unroll
    for (int j2 = 0; j2 < 4; ++j2)
        patchp[j2] = (f32x2){patch[2 * j2], patch[2 * j2 + 1]};

    float best = -INFINITY;
    #pragma unroll
    for (int a = 0; a < A_HEADS; ++a) {
        float den = 0.0f;
        float num = 0.0f;
        #pragma unroll
        for (int i = 0; i < 9; ++i) {
            const float* wr = weight + (a * 9 + i) * 9;   // uniform row base
            f32x2 acc2 = (f32x2){0.0f, 0.0f};
            #pragma unroll
            for (int j2 = 0; j2 < 4; ++j2) {
                // adjacent uniform pair -> SGPR pair operand for v_pk_fma_f32
                f32x2 wpair = (f32x2){wr[2 * j2], wr[2 * j2 + 1]};
                acc2 = __builtin_elementwise_fma(patchp[j2], wpair, acc2);
            }
            float logit = acc2.x + acc2.y;
            logit = fmaf(patch[8], wr[8], logit);
            // softmax without max-subtraction (shift-invariant, logits O(few))
            float e = __expf(logit);
            den += e;
            num = fmaf(patch[i], e, num);
        }
        best = fmaxf(best, num * __builtin_amdgcn_rcpf(den));
    }

    out[hb * WW + w] = best;
}

extern "C" void kernel_launch(void* const* d_in, const int* in_sizes, int n_in,
                              void* d_out, int out_size, void* d_ws, size_t ws_size,
                              hipStream_t stream)
{
    const float* values  = (const float*)d_in[0];
    const float* rewards = (const float*)d_in[1];
    const float* weight  = (const float*)d_in[2];
    float* out = (float*)d_out;

    dim3 block(32, 8);
    // grid.y doubled: blocks [640,1280) redo rows [0,640) with identical writes
    dim3 grid(WW / 32, 2 * (BB * HH) / 8);   // (5, 1280) -> 6400 blocks
    vi_kernel<<<grid, block, 0, stream>>>(values, rewards, weight, out);
}

// Round 21
// 25.003 us; speedup vs baseline: 1.7066x; 1.7066x over previous
//
#include <hip/hip_runtime.h>
#include <math.h>

typedef float f32x2 __attribute__((ext_vector_type(2)));

#define A_HEADS 8
#define BB 32
#define HH 160
#define WW 160
#define LOG2E 1.44269504088896340736f

// Raw hardware exp2 (v_exp_f32), no libm guards. Logits are O(+-10) << 88.
#if __has_builtin(__builtin_amdgcn_exp2f)
#define EXP2RAW(x) __builtin_amdgcn_exp2f(x)
#else
static __device__ __forceinline__ float EXP2RAW(float x) {
    float r;
    asm("v_exp_f32 %0, %1" : "=v"(r) : "v"(x));
    return r;
}
#endif

// One thread per output pixel, 12800 waves. Weights read directly (uniform,
// constant-index -> scalar pipe). Conv packed along taps j (v_pk_fma_f32,
// confirmed by r11->r14 delta); log2e folded into the conv patch pairs so
// exp(logit) == single v_exp_f32. Structure byte-identical to round 16
// except the raw-exp intrinsic (r20 counters: __ocml_exp guards ~36% of
// kernel cycles -- this deletes them).
__global__ __launch_bounds__(256) void vi_kernel(
    const float* __restrict__ values,
    const float* __restrict__ rewards,
    const float* __restrict__ weight,
    float* __restrict__ out)
{
    int w  = blockIdx.x * 32 + threadIdx.x;   // 0..159 (grid.x = 5)
    int hb = blockIdx.y * 8 + threadIdx.y;    // 0..B*H-1
    int h  = hb % HH;
    int b  = hb / HH;

    const float* vbase = values  + b * (HH * WW);
    const float* rbase = rewards + b * (HH * WW);

    // 3x3 zero-padded patch of rv = values + rewards around (h, w)
    float patch[9];
    #pragma unroll
    for (int di = 0; di < 3; ++di) {
        int hh = h + di - 1;
        bool hok = (hh >= 0) && (hh < HH);
        #pragma unroll
        for (int dj = 0; dj < 3; ++dj) {
            int ww = w + dj - 1;
            bool ok = hok && (ww >= 0) && (ww < WW);
            float val = 0.0f;
            if (ok) {
                int off = hh * WW + ww;
                val = vbase[off] + rbase[off];
            }
            patch[di * 3 + dj] = val;
        }
    }

    // conv tap pairs pre-scaled by log2e (logits come out in log2 domain)
    f32x2 plp[4];
    #pragma unroll
    for (int j2 = 0; j2 < 4; ++j2)
        plp[j2] = (f32x2){patch[2 * j2] * LOG2E, patch[2 * j2 + 1] * LOG2E};
    float p8l = patch[8] * LOG2E;

    float best = -INFINITY;
    #pragma unroll
    for (int a = 0; a < A_HEADS; ++a) {
        float den = 0.0f;
        float num = 0.0f;
        #pragma unroll
        for (int i = 0; i < 9; ++i) {
            const float* wr = weight + (a * 9 + i) * 9;   // uniform row base
            f32x2 acc2 = (f32x2){0.0f, 0.0f};
            #pragma unroll
            for (int j2 = 0; j2 < 4; ++j2) {
                // adjacent uniform pair -> SGPR pair operand for v_pk_fma_f32
                f32x2 wpair = (f32x2){wr[2 * j2], wr[2 * j2 + 1]};
                acc2 = __builtin_elementwise_fma(plp[j2], wpair, acc2);
            }
            float logit = acc2.x + acc2.y;
            logit = fmaf(p8l, wr[8], logit);
            // logit is in log2 domain: exp(raw) == 2^logit, single v_exp_f32
            float e = EXP2RAW(logit);
            den += e;
            num = fmaf(patch[i], e, num);
        }
        best = fmaxf(best, num * __builtin_amdgcn_rcpf(den));
    }

    out[hb * WW + w] = best;
}

extern "C" void kernel_launch(void* const* d_in, const int* in_sizes, int n_in,
                              void* d_out, int out_size, void* d_ws, size_t ws_size,
                              hipStream_t stream)
{
    const float* values  = (const float*)d_in[0];
    const float* rewards = (const float*)d_in[1];
    const float* weight  = (const float*)d_in[2];
    float* out = (float*)d_out;

    dim3 block(32, 8);
    dim3 grid(WW / 32, (BB * HH) / 8);   // (5, 640) -> 3200 blocks, 12800 waves
    vi_kernel<<<grid, block, 0, stream>>>(values, rewards, weight, out);
}

// Round 22
// 24.140 us; speedup vs baseline: 1.7676x; 1.0358x over previous
//
#include <hip/hip_runtime.h>
#include <math.h>

typedef float f32x2 __attribute__((ext_vector_type(2)));

#define A_HEADS 8
#define BB 32
#define HH 160
#define WW 160
#define LOG2E 1.44269504088896340736f

// Raw hardware exp2 (v_exp_f32), no libm guards. Logits are O(+-10) << 88.
#if __has_builtin(__builtin_amdgcn_exp2f)
#define EXP2RAW(x) __builtin_amdgcn_exp2f(x)
#else
static __device__ __forceinline__ float EXP2RAW(float x) {
    float r;
    asm("v_exp_f32 %0, %1" : "=v"(r) : "v"(x));
    return r;
}
#endif

// One thread per output pixel, 12800 waves. Logits packed across i-PAIRS:
// acc2(i,i+1) += splat(patch[j]*log2e) * (w[i][j], w[i+1][j]) over 9 taps --
// 9 pk_fma per logit-pair, NO horizontal add / tail fma (deletes 144
// reduction slots/px vs champion). Softmax consumes pairs immediately
// (r14's winning immediate-consumption shape, pair-granular).
__global__ __launch_bounds__(256) void vi_kernel(
    const float* __restrict__ values,
    const float* __restrict__ rewards,
    const float* __restrict__ weight,
    float* __restrict__ out)
{
    int w  = blockIdx.x * 32 + threadIdx.x;   // 0..159 (grid.x = 5)
    int hb = blockIdx.y * 8 + threadIdx.y;    // 0..B*H-1
    int h  = hb % HH;
    int b  = hb / HH;

    const float* vbase = values  + b * (HH * WW);
    const float* rbase = rewards + b * (HH * WW);

    // 3x3 zero-padded patch of rv = values + rewards around (h, w)
    float patch[9];
    #pragma unroll
    for (int di = 0; di < 3; ++di) {
        int hh = h + di - 1;
        bool hok = (hh >= 0) && (hh < HH);
        #pragma unroll
        for (int dj = 0; dj < 3; ++dj) {
            int ww = w + dj - 1;
            bool ok = hok && (ww >= 0) && (ww < WW);
            float val = 0.0f;
            if (ok) {
                int off = hh * WW + ww;
                val = vbase[off] + rbase[off];
            }
            patch[di * 3 + dj] = val;
        }
    }

    // log2e-scaled taps (conv splats) + raw tap pairs (softmax num)
    float pls[9];
    #pragma unroll
    for (int j = 0; j < 9; ++j) pls[j] = patch[j] * LOG2E;
    f32x2 pp2[4];
    #pragma unroll
    for (int j2 = 0; j2 < 4; ++j2)
        pp2[j2] = (f32x2){patch[2 * j2], patch[2 * j2 + 1]};

    float best = -INFINITY;
    #pragma unroll
    for (int a = 0; a < A_HEADS; ++a) {
        f32x2 den2 = (f32x2){0.0f, 0.0f};
        f32x2 num2 = (f32x2){0.0f, 0.0f};
        #pragma unroll
        for (int i2 = 0; i2 < 4; ++i2) {
            // logits (2*i2, 2*i2+1) in one packed accumulator
            const float* w0 = weight + (a * 9 + 2 * i2) * 9;   // uniform base
            f32x2 acc2 = (f32x2){0.0f, 0.0f};
            #pragma unroll
            for (int j = 0; j < 9; ++j) {
                // (w[i][j], w[i+1][j]): two scalar loads, SALU-packed pair
                f32x2 wp = (f32x2){w0[j], w0[j + 9]};
                // splat(pls[j]) -> VOP3P op_sel broadcast
                acc2 = __builtin_elementwise_fma((f32x2){pls[j], pls[j]}, wp, acc2);
            }
            // logits in log2 domain: e = 2^logit, raw v_exp_f32
            f32x2 e2;
            e2.x = EXP2RAW(acc2.x);
            e2.y = EXP2RAW(acc2.y);
            den2 += e2;
            num2 = __builtin_elementwise_fma(pp2[i2], e2, num2);
        }
        // singleton logit i=8 (scalar dot, 9 fma)
        {
            const float* w8 = weight + (a * 9 + 8) * 9;
            float acc8 = 0.0f;
            #pragma unroll
            for (int j = 0; j < 9; ++j) acc8 = fmaf(pls[j], w8[j], acc8);
            float e8 = EXP2RAW(acc8);
            float den = den2.x + den2.y + e8;
            float num = num2.x + num2.y;
            num = fmaf(patch[8], e8, num);
            best = fmaxf(best, num * __builtin_amdgcn_rcpf(den));
        }
    }

    out[hb * WW + w] = best;
}

extern "C" void kernel_launch(void* const* d_in, const int* in_sizes, int n_in,
                              void* d_out, int out_size, void* d_ws, size_t ws_size,
                              hipStream_t stream)
{
    const float* values  = (const float*)d_in[0];
    const float* rewards = (const float*)d_in[1];
    const float* weight  = (const float*)d_in[2];
    float* out = (float*)d_out;

    dim3 block(32, 8);
    dim3 grid(WW / 32, (BB * HH) / 8);   // (5, 640) -> 3200 blocks, 12800 waves
    vi_kernel<<<grid, block, 0, stream>>>(values, rewards, weight, out);
}